// Round 8
// baseline (1631.325 us; speedup 1.0000x reference)
//
#include <hip/hip_runtime.h>
#include <cstdint>
#include <cstddef>

typedef unsigned short u16;
typedef short short8 __attribute__((ext_vector_type(8)));
typedef __bf16 bf16x8 __attribute__((ext_vector_type(8)));
typedef float f32x4 __attribute__((ext_vector_type(4)));

#define TOKENS 32768
#define DMODEL 384
#define DINNER 768
#define HIDDEN_DIM 1536
#define LSEQ 4096
#define NBATCH 8

__device__ __forceinline__ float bf2f(u16 h) {
  return __uint_as_float(((unsigned)h) << 16);
}
__device__ __forceinline__ u16 f2bf(float f) {
  unsigned x = __float_as_uint(f);
  unsigned r = x + 0x7fffu + ((x >> 16) & 1u);
  return (u16)(r >> 16);
}

__device__ __forceinline__ void gload_lds16(const void* g, void* l) {
  __builtin_amdgcn_global_load_lds(
      (const __attribute__((address_space(1))) unsigned int*)g,
      (__attribute__((address_space(3))) unsigned int*)l, 16, 0, 0);
}

__device__ __forceinline__ f32x4 mfma16(short8 a, short8 b, f32x4 c) {
  return __builtin_amdgcn_mfma_f32_16x16x32_bf16(
      __builtin_bit_cast(bf16x8, a), __builtin_bit_cast(bf16x8, b), c, 0, 0, 0);
}

// ---------------- weight conversion ----------------
__global__ void k_f2bf(const float* __restrict__ in, u16* __restrict__ out, int n) {
  int i = blockIdx.x * 256 + threadIdx.x;
  int stride = gridDim.x * 256;
  for (; i < n; i += stride) out[i] = f2bf(in[i]);
}

// pad w_xproj (56x768) -> (64x768) bf16, rows 56..63 zero
__global__ void k_pad_wxp(const float* __restrict__ in, u16* __restrict__ out) {
  int i = blockIdx.x * 256 + threadIdx.x;
  if (i >= 64 * 768) return;
  int r = i / 768, c = i - r * 768;
  out[i] = (r < 56) ? f2bf(in[r * 768 + c]) : (u16)0;
}

// ---------------- rmsnorm (f32 in -> bf16 out), 1 wave per token ----------------
__global__ __launch_bounds__(256) void k_rmsnorm(const float* __restrict__ x,
                                                 const float* __restrict__ w,
                                                 u16* __restrict__ out) {
  int lane = threadIdx.x & 63;
  size_t tok = (size_t)blockIdx.x * 4 + (threadIdx.x >> 6);
  const float* xr = x + tok * DMODEL;
  float v[6];
  float ss = 0.f;
#pragma unroll
  for (int i = 0; i < 6; ++i) {
    v[i] = xr[lane + 64 * i];
    ss = fmaf(v[i], v[i], ss);
  }
#pragma unroll
  for (int off = 32; off; off >>= 1) ss += __shfl_xor(ss, off);
  float sc = rsqrtf(ss * (1.f / (float)DMODEL) + 1e-5f);
  u16* orow = out + tok * DMODEL;
#pragma unroll
  for (int i = 0; i < 6; ++i) orow[lane + 64 * i] = f2bf(v[i] * sc * w[lane + 64 * i]);
}

// ---------------- GEMM: C[M,N] = A[M,K](bf16) @ Bt[N,K](bf16)^T, epilogues ----------------
// EPI 0: split cols<768 -> outh0 (u_pre), >=768 -> outh1 (z), bf16
// EPI 1: outf[row*64+col] = v (padded x_dbl, f32)
// EPI 2: outf[row*N+col] = aux[row*N+col] + v   (residual add, f32)
// EPI 3: outh0[row*N+col] = bf16(gelu_exact(v + aux[col]))
// EPI 4: outf[row*N+col] += v + aux[col]        (final residual += mlp)
template <int BN, int EPI>
__global__ __launch_bounds__(256) void k_gemm_bt(
    const u16* __restrict__ A, const u16* __restrict__ Bt, int K, int N, int gridM,
    const float* __restrict__ aux, float* __restrict__ outf,
    u16* __restrict__ outh0, u16* __restrict__ outh1) {
  static_assert(BN == 64 || BN == 128, "BN");
  constexpr int NF = BN / 32;  // n-fragments per wave (wave tile = 64 x BN/2)
  __shared__ __align__(16) u16 As[128 * 32];
  __shared__ __align__(16) u16 Bs[BN * 32];
  const int tid = threadIdx.x;
  const int lane = tid & 63;
  const int w = tid >> 6;
  const int wm = w >> 1, wn = w & 1;
  const int mb = blockIdx.x % gridM;
  const int nb = blockIdx.x / gridM;
  const size_t m0 = (size_t)mb * 128, n0 = (size_t)nb * BN;

  f32x4 acc[4][NF];
#pragma unroll
  for (int m = 0; m < 4; ++m)
#pragma unroll
    for (int n = 0; n < NF; ++n) acc[m][n] = (f32x4){0.f, 0.f, 0.f, 0.f};

  const int r4 = tid >> 2, c4 = tid & 3;
  const u16* ga = A + (m0 + r4) * (size_t)K + c4 * 8;
  const u16* gb = Bt + (n0 + r4) * (size_t)K + c4 * 8;
  const int fr = lane & 15, fk = lane >> 4;

  for (int kt = 0; kt < K; kt += 32) {
    gload_lds16(ga + kt, &As[tid * 8]);
    gload_lds16(ga + (size_t)64 * K + kt, &As[2048 + tid * 8]);
    gload_lds16(gb + kt, &Bs[tid * 8]);
    if constexpr (BN == 128) gload_lds16(gb + (size_t)64 * K + kt, &Bs[2048 + tid * 8]);
    __syncthreads();
    short8 afr[4], bfr[NF];
#pragma unroll
    for (int m = 0; m < 4; ++m)
      afr[m] = *(const short8*)&As[(wm * 64 + m * 16 + fr) * 32 + fk * 8];
#pragma unroll
    for (int n = 0; n < NF; ++n)
      bfr[n] = *(const short8*)&Bs[(wn * (BN / 2) + n * 16 + fr) * 32 + fk * 8];
#pragma unroll
    for (int m = 0; m < 4; ++m)
#pragma unroll
      for (int n = 0; n < NF; ++n) acc[m][n] = mfma16(afr[m], bfr[n], acc[m][n]);
    __syncthreads();
  }

  const int cc = lane & 15, cr = (lane >> 4) * 4;
#pragma unroll
  for (int m = 0; m < 4; ++m)
#pragma unroll
    for (int n = 0; n < NF; ++n)
#pragma unroll
      for (int j = 0; j < 4; ++j) {
        size_t row = m0 + wm * 64 + m * 16 + cr + j;
        size_t col = n0 + wn * (BN / 2) + n * 16 + cc;
        float v = acc[m][n][j];
        if constexpr (EPI == 0) {
          if (col < DINNER) outh0[row * DINNER + col] = f2bf(v);
          else outh1[row * DINNER + (col - DINNER)] = f2bf(v);
        } else if constexpr (EPI == 1) {
          outf[row * 64 + col] = v;
        } else if constexpr (EPI == 2) {
          outf[row * (size_t)N + col] = aux[row * (size_t)N + col] + v;
        } else if constexpr (EPI == 3) {
          float t = v + aux[col];
          float g = 0.5f * t * (1.f + erff(t * 0.70710678118654752f));
          outh0[row * (size_t)N + col] = f2bf(g);
        } else if constexpr (EPI == 4) {
          outf[row * (size_t)N + col] += v + aux[col];
        }
      }
}

// ---------------- depthwise causal conv(4) + bias + silu, bf16 in/out ----------------
__global__ __launch_bounds__(256) void k_conv(const u16* __restrict__ upre,
                                              const float* __restrict__ cw,
                                              const float* __restrict__ cb,
                                              u16* __restrict__ u) {
  int tid = threadIdx.x;
  int d = blockIdx.x * 256 + tid;
  int l0 = blockIdx.y * 16;
  int b = blockIdx.z;
  size_t tokbase = (size_t)b * LSEQ;
  float s[19];
#pragma unroll
  for (int r = 0; r < 19; ++r) {
    int gl = l0 - 3 + r;
    s[r] = (gl >= 0) ? bf2f(upre[(tokbase + gl) * DINNER + d]) : 0.f;
  }
  float w0 = cw[d * 4 + 0], w1 = cw[d * 4 + 1], w2 = cw[d * 4 + 2], w3 = cw[d * 4 + 3];
  float bias = cb[d];
#pragma unroll
  for (int i = 0; i < 16; ++i) {
    float a = bias + w0 * s[i] + w1 * s[i + 1] + w2 * s[i + 2] + w3 * s[i + 3];
    float sig = 1.f / (1.f + __expf(-a));
    u[(tokbase + l0 + i) * DINNER + d] = f2bf(a * sig);
  }
}

// ---------------- dt_proj + softplus -> delta (bf16) ----------------
__global__ __launch_bounds__(256) void k_dtproj(const float* __restrict__ xdbl,
                                                const u16* __restrict__ wdt,
                                                const float* __restrict__ bdt,
                                                u16* __restrict__ delta) {
  __shared__ __align__(16) u16 wsm[768 * 24];
  __shared__ __align__(16) float dts[32][24];
  int tid = threadIdx.x;
  for (int i = tid; i < 768 * 24; i += 256) wsm[i] = wdt[i];
  int tok0 = blockIdx.x * 32;
  for (int i = tid; i < 32 * 24; i += 256) {
    int t = i / 24, r = i - t * 24;
    dts[t][r] = xdbl[(size_t)(tok0 + t) * 64 + r];
  }
  __syncthreads();
  for (int dd = 0; dd < 3; ++dd) {
    int d = dd * 256 + tid;
    float wreg[24];
#pragma unroll
    for (int r = 0; r < 24; ++r) wreg[r] = bf2f(wsm[d * 24 + r]);
    float bias = bdt[d];
    for (int t = 0; t < 32; ++t) {
      float acc = bias;
#pragma unroll
      for (int r = 0; r < 24; ++r) acc = fmaf(dts[t][r], wreg[r], acc);
      float sp = (acc > 20.f) ? acc : log1pf(__expf(acc));
      delta[(size_t)(tok0 + t) * DINNER + d] = f2bf(sp);
    }
  }
}

// ---------------- selective scan + gating: y = (scan + u*D) * silu(z), bf16 out ----------------
// block: 256 thr = 4 waves; wave = 4 channels x 16 states; block = 16 channels (one d-group) of one batch
__global__ __launch_bounds__(256) void k_scan(
    const u16* __restrict__ delta, const u16* __restrict__ u,
    const float* __restrict__ xdbl, const u16* __restrict__ z,
    const float* __restrict__ A_log, const float* __restrict__ Dvec,
    u16* __restrict__ y) {
  __shared__ __align__(16) float sd[64][16];
  __shared__ __align__(16) float su[64][16];
  __shared__ __align__(16) float sB[64][16];
  __shared__ __align__(16) float sC[64][16];
  __shared__ __align__(16) float sz[64][16];
  __shared__ __align__(16) float sy[64][16];
  int bid = blockIdx.x;
  int b = bid / 48, dg = bid - b * 48;
  int d0 = dg * 16;
  int tid = threadIdx.x;
  int lane = tid & 63, w = tid >> 6;
  int ch = (w << 2) | (lane >> 4);
  int s = lane & 15;
  int d = d0 + ch;
  float A_ds = -__expf(A_log[d * 16 + s]);
  float Dd = Dvec[d];
  float h = 0.f;
  int le = tid >> 2;
  int je = (tid & 3) << 2;
  size_t tb = (size_t)b * LSEQ;

  // prologue: load + store chunk 0
  float4 Bv, Cv;
  ushort4 dv, uv, zv;
  {
    size_t tok = tb + le;
    dv = *(const ushort4*)&delta[tok * DINNER + d0 + je];
    uv = *(const ushort4*)&u[tok * DINNER + d0 + je];
    zv = *(const ushort4*)&z[tok * DINNER + d0 + je];
    Bv = *(const float4*)&xdbl[tok * 64 + 24 + je];
    Cv = *(const float4*)&xdbl[tok * 64 + 40 + je];
    sd[le][je + 0] = bf2f(dv.x); sd[le][je + 1] = bf2f(dv.y);
    sd[le][je + 2] = bf2f(dv.z); sd[le][je + 3] = bf2f(dv.w);
    su[le][je + 0] = bf2f(uv.x); su[le][je + 1] = bf2f(uv.y);
    su[le][je + 2] = bf2f(uv.z); su[le][je + 3] = bf2f(uv.w);
    sz[le][je + 0] = bf2f(zv.x); sz[le][je + 1] = bf2f(zv.y);
    sz[le][je + 2] = bf2f(zv.z); sz[le][je + 3] = bf2f(zv.w);
    *(float4*)&sB[le][je] = Bv;
    *(float4*)&sC[le][je] = Cv;
  }

  for (int l0 = 0; l0 < LSEQ; l0 += 64) {
    bool more = (l0 + 64) < LSEQ;
    if (more) {  // prefetch next chunk into regs (overlaps with compute)
      size_t tok = tb + l0 + 64 + le;
      dv = *(const ushort4*)&delta[tok * DINNER + d0 + je];
      uv = *(const ushort4*)&u[tok * DINNER + d0 + je];
      zv = *(const ushort4*)&z[tok * DINNER + d0 + je];
      Bv = *(const float4*)&xdbl[tok * 64 + 24 + je];
      Cv = *(const float4*)&xdbl[tok * 64 + 40 + je];
    }
    __syncthreads();  // LDS chunk ready
#pragma unroll 4
    for (int l = 0; l < 64; ++l) {
      float dvx = sd[l][ch];
      float uvx = su[l][ch];
      float dA = __expf(dvx * A_ds);
      float binp = dvx * uvx * sB[l][s];
      h = fmaf(dA, h, binp);
      float yc = h * sC[l][s];
      yc += __shfl_xor(yc, 1);
      yc += __shfl_xor(yc, 2);
      yc += __shfl_xor(yc, 4);
      yc += __shfl_xor(yc, 8);
      if (s == 0) {
        float zvx = sz[l][ch];
        float gate = zvx / (1.f + __expf(-zvx));
        sy[l][ch] = (yc + uvx * Dd) * gate;
      }
    }
    __syncthreads();  // sy complete; safe to overwrite staging
    {  // write y chunk
      size_t tok = tb + l0 + le;
      ushort4 o;
      o.x = f2bf(sy[le][je + 0]); o.y = f2bf(sy[le][je + 1]);
      o.z = f2bf(sy[le][je + 2]); o.w = f2bf(sy[le][je + 3]);
      *(ushort4*)&y[tok * DINNER + d0 + je] = o;
    }
    if (more) {  // stage next chunk to LDS
      sd[le][je + 0] = bf2f(dv.x); sd[le][je + 1] = bf2f(dv.y);
      sd[le][je + 2] = bf2f(dv.z); sd[le][je + 3] = bf2f(dv.w);
      su[le][je + 0] = bf2f(uv.x); su[le][je + 1] = bf2f(uv.y);
      su[le][je + 2] = bf2f(uv.z); su[le][je + 3] = bf2f(uv.w);
      sz[le][je + 0] = bf2f(zv.x); sz[le][je + 1] = bf2f(zv.y);
      sz[le][je + 2] = bf2f(zv.z); sz[le][je + 3] = bf2f(zv.w);
      *(float4*)&sB[le][je] = Bv;
      *(float4*)&sC[le][je] = Cv;
    }
  }
}

// ---------------- launch ----------------
// Workspace budget (~180 MiB; was ~348 MiB — round-3 run died with a device
// page-fault abort, prime suspect was d_ws overflow):
//   x1n   25 MB  [rms1 -> in_proj]      ; reused as x2n [rms2 -> fc1]
//   upre  48 MB  [in_proj -> conv]      ; reused as delta(bf16) [dtproj -> scan]
//   u     48 MB  [conv -> scan]         ; reused as h1 lower half [fc1 -> fc2]
//   y     48 MB  [scan -> out_proj]     ; reused as h1 upper half (contiguous with u)
//   xdbl   8 MB  [x_proj -> scan]
//   z     -> lives in d_out (dead before out_proj overwrites d_out)
//   weights ~4.3 MB
extern "C" void kernel_launch(void* const* d_in, const int* in_sizes, int n_in,
                              void* d_out, int out_size, void* d_ws, size_t ws_size,
                              hipStream_t stream) {
  (void)in_sizes; (void)n_in; (void)out_size; (void)ws_size;
  const float* x       = (const float*)d_in[0];
  const float* norm1_w = (const float*)d_in[1];
  const float* w_in    = (const float*)d_in[2];
  const float* conv_w  = (const float*)d_in[3];
  const float* conv_b  = (const float*)d_in[4];
  const float* w_xproj = (const float*)d_in[5];
  const float* w_dt    = (const float*)d_in[6];
  const float* b_dt    = (const float*)d_in[7];
  const float* A_log   = (const float*)d_in[8];
  const float* Dv      = (const float*)d_in[9];
  const float* w_out   = (const float*)d_in[10];
  const float* norm2_w = (const float*)d_in[11];
  const float* fc1_w   = (const float*)d_in[12];
  const float* fc1_b   = (const float*)d_in[13];
  const float* fc2_w   = (const float*)d_in[14];
  const float* fc2_b   = (const float*)d_in[15];
  float* out = (float*)d_out;

  char* ws = (char*)d_ws;
  size_t off = 0;
  auto alloc = [&](size_t bytes) {
    char* p = ws + off;
    off += (bytes + 255) & ~(size_t)255;
    return p;
  };
  u16* x1n    = (u16*)alloc((size_t)TOKENS * DMODEL * 2);   // also x2n
  u16* upre   = (u16*)alloc((size_t)TOKENS * DINNER * 2);   // also delta (bf16)
  u16* u      = (u16*)alloc((size_t)TOKENS * DINNER * 2);   // also h1[:, :768]
  u16* y      = (u16*)alloc((size_t)TOKENS * DINNER * 2);   // also h1[:, 768:]
  float* xdbl = (float*)alloc((size_t)TOKENS * 64 * 4);
  u16* w_in_h = (u16*)alloc((size_t)1536 * 384 * 2);
  u16* wxp_h  = (u16*)alloc((size_t)64 * 768 * 2);
  u16* wdt_h  = (u16*)alloc((size_t)768 * 24 * 2);
  u16* w_out_h= (u16*)alloc((size_t)384 * 768 * 2);
  u16* fc1_h  = (u16*)alloc((size_t)1536 * 384 * 2);
  u16* fc2_h  = (u16*)alloc((size_t)384 * 1536 * 2);
  u16* z      = (u16*)d_out;  // 32768*768*2 B == 32768*384*4 B exactly
  u16* delta_h = upre;        // upre dead after conv
  u16* h1 = u;                // u (dead after scan) ∥ y (dead after out_proj), contiguous
  u16* x2n = x1n;             // x1n dead after in_proj

  // weight conversions (each call; ws is re-poisoned every launch)
  k_f2bf<<<256, 256, 0, stream>>>(w_in, w_in_h, 1536 * 384);
  k_pad_wxp<<<(64 * 768 + 255) / 256, 256, 0, stream>>>(w_xproj, wxp_h);
  k_f2bf<<<72, 256, 0, stream>>>(w_dt, wdt_h, 768 * 24);
  k_f2bf<<<256, 256, 0, stream>>>(w_out, w_out_h, 384 * 768);
  k_f2bf<<<256, 256, 0, stream>>>(fc1_w, fc1_h, 1536 * 384);
  k_f2bf<<<256, 256, 0, stream>>>(fc2_w, fc2_h, 384 * 1536);

  // 1) rmsnorm1
  k_rmsnorm<<<TOKENS / 4, 256, 0, stream>>>(x, norm1_w, x1n);
  // 2) in_proj -> u_pre, z(in d_out)
  k_gemm_bt<128, 0><<<256 * 12, 256, 0, stream>>>(x1n, w_in_h, 384, 1536, 256,
                                                  nullptr, nullptr, upre, z);
  // 3) conv + silu -> u
  dim3 cgrid(3, 256, 8);
  k_conv<<<cgrid, 256, 0, stream>>>(upre, conv_w, conv_b, u);
  // 4) x_proj -> xdbl (padded stride 64)
  k_gemm_bt<64, 1><<<256 * 1, 256, 0, stream>>>(u, wxp_h, 768, 64, 256,
                                                nullptr, xdbl, nullptr, nullptr);
  // 5) dt_proj + softplus -> delta (bf16, in upre region)
  k_dtproj<<<TOKENS / 32, 256, 0, stream>>>(xdbl, wdt_h, b_dt, delta_h);
  // 6) selective scan + gating -> y
  k_scan<<<NBATCH * 48, 256, 0, stream>>>(delta_h, u, xdbl, z, A_log, Dv, y);
  // 7) out_proj + residual -> d_out (= x2); overwrites z region
  k_gemm_bt<128, 2><<<256 * 3, 256, 0, stream>>>(y, w_out_h, 768, 384, 256,
                                                 x, out, nullptr, nullptr);
  // 8) rmsnorm2
  k_rmsnorm<<<TOKENS / 4, 256, 0, stream>>>(out, norm2_w, x2n);
  // 9) fc1 + gelu -> h1 (over u∥y)
  k_gemm_bt<128, 3><<<256 * 12, 256, 0, stream>>>(x2n, fc1_h, 384, 1536, 256,
                                                  fc1_b, nullptr, h1, nullptr);
  // 10) fc2 + bias + residual -> d_out
  k_gemm_bt<128, 4><<<256 * 3, 256, 0, stream>>>(h1, fc2_h, 1536, 384, 256,
                                                 fc2_b, out, nullptr, nullptr);
}

// Round 9
// 1175.700 us; speedup vs baseline: 1.3875x; 1.3875x over previous
//
#include <hip/hip_runtime.h>
#include <cstdint>
#include <cstddef>

typedef unsigned short u16;
typedef short short8 __attribute__((ext_vector_type(8)));
typedef __bf16 bf16x8 __attribute__((ext_vector_type(8)));
typedef float f32x4 __attribute__((ext_vector_type(4)));

#define TOKENS 32768
#define DMODEL 384
#define DINNER 768
#define HIDDEN_DIM 1536
#define LSEQ 4096
#define NBATCH 8
#define NC 8           // scan chunks per sequence
#define CHUNK 512      // LSEQ / NC
#define SUB 64         // timesteps staged per LDS round

__device__ __forceinline__ float bf2f(u16 h) {
  return __uint_as_float(((unsigned)h) << 16);
}
__device__ __forceinline__ u16 f2bf(float f) {
  unsigned x = __float_as_uint(f);
  unsigned r = x + 0x7fffu + ((x >> 16) & 1u);
  return (u16)(r >> 16);
}

__device__ __forceinline__ void gload_lds16(const void* g, void* l) {
  __builtin_amdgcn_global_load_lds(
      (const __attribute__((address_space(1))) unsigned int*)g,
      (__attribute__((address_space(3))) unsigned int*)l, 16, 0, 0);
}

__device__ __forceinline__ f32x4 mfma16(short8 a, short8 b, f32x4 c) {
  return __builtin_amdgcn_mfma_f32_16x16x32_bf16(
      __builtin_bit_cast(bf16x8, a), __builtin_bit_cast(bf16x8, b), c, 0, 0, 0);
}

// 16-lane (DPP row) butterfly sum: after 4 steps every lane of each 16-lane
// row holds the row sum. xor1,xor2 via quad_perm; xor{rest} via row mirrors.
template <int CTRL>
__device__ __forceinline__ float dppadd(float x) {
  int t = __builtin_amdgcn_update_dpp(0, __builtin_bit_cast(int, x), CTRL, 0xF, 0xF, true);
  return x + __builtin_bit_cast(float, t);
}
__device__ __forceinline__ float row16_sum(float x) {
  x = dppadd<0xB1>(x);   // quad_perm [1,0,3,2]  : xor 1
  x = dppadd<0x4E>(x);   // quad_perm [2,3,0,1]  : xor 2
  x = dppadd<0x140>(x);  // row_mirror           : + quad q^3
  x = dppadd<0x141>(x);  // row_half_mirror      : + quads q^1,q^2
  return x;
}

// ---------------- weight conversion ----------------
__global__ void k_f2bf(const float* __restrict__ in, u16* __restrict__ out, int n) {
  int i = blockIdx.x * 256 + threadIdx.x;
  int stride = gridDim.x * 256;
  for (; i < n; i += stride) out[i] = f2bf(in[i]);
}

// pad w_xproj (56x768) -> (64x768) bf16, rows 56..63 zero
__global__ void k_pad_wxp(const float* __restrict__ in, u16* __restrict__ out) {
  int i = blockIdx.x * 256 + threadIdx.x;
  if (i >= 64 * 768) return;
  int r = i / 768, c = i - r * 768;
  out[i] = (r < 56) ? f2bf(in[r * 768 + c]) : (u16)0;
}

// ---------------- rmsnorm (f32 in -> bf16 out), 1 wave per token ----------------
__global__ __launch_bounds__(256) void k_rmsnorm(const float* __restrict__ x,
                                                 const float* __restrict__ w,
                                                 u16* __restrict__ out) {
  int lane = threadIdx.x & 63;
  size_t tok = (size_t)blockIdx.x * 4 + (threadIdx.x >> 6);
  const float* xr = x + tok * DMODEL;
  float v[6];
  float ss = 0.f;
#pragma unroll
  for (int i = 0; i < 6; ++i) {
    v[i] = xr[lane + 64 * i];
    ss = fmaf(v[i], v[i], ss);
  }
#pragma unroll
  for (int off = 32; off; off >>= 1) ss += __shfl_xor(ss, off);
  float sc = rsqrtf(ss * (1.f / (float)DMODEL) + 1e-5f);
  u16* orow = out + tok * DMODEL;
#pragma unroll
  for (int i = 0; i < 6; ++i) orow[lane + 64 * i] = f2bf(v[i] * sc * w[lane + 64 * i]);
}

// ---------------- GEMM: C[M,N] = A[M,K](bf16) @ Bt[N,K](bf16)^T, epilogues ----------------
template <int BN, int EPI>
__global__ __launch_bounds__(256) void k_gemm_bt(
    const u16* __restrict__ A, const u16* __restrict__ Bt, int K, int N, int gridM,
    const float* __restrict__ aux, float* __restrict__ outf,
    u16* __restrict__ outh0, u16* __restrict__ outh1) {
  static_assert(BN == 64 || BN == 128, "BN");
  constexpr int NF = BN / 32;
  __shared__ __align__(16) u16 As[128 * 32];
  __shared__ __align__(16) u16 Bs[BN * 32];
  const int tid = threadIdx.x;
  const int lane = tid & 63;
  const int w = tid >> 6;
  const int wm = w >> 1, wn = w & 1;
  const int mb = blockIdx.x % gridM;
  const int nb = blockIdx.x / gridM;
  const size_t m0 = (size_t)mb * 128, n0 = (size_t)nb * BN;

  f32x4 acc[4][NF];
#pragma unroll
  for (int m = 0; m < 4; ++m)
#pragma unroll
    for (int n = 0; n < NF; ++n) acc[m][n] = (f32x4){0.f, 0.f, 0.f, 0.f};

  const int r4 = tid >> 2, c4 = tid & 3;
  const u16* ga = A + (m0 + r4) * (size_t)K + c4 * 8;
  const u16* gb = Bt + (n0 + r4) * (size_t)K + c4 * 8;
  const int fr = lane & 15, fk = lane >> 4;

  for (int kt = 0; kt < K; kt += 32) {
    gload_lds16(ga + kt, &As[tid * 8]);
    gload_lds16(ga + (size_t)64 * K + kt, &As[2048 + tid * 8]);
    gload_lds16(gb + kt, &Bs[tid * 8]);
    if constexpr (BN == 128) gload_lds16(gb + (size_t)64 * K + kt, &Bs[2048 + tid * 8]);
    __syncthreads();
    short8 afr[4], bfr[NF];
#pragma unroll
    for (int m = 0; m < 4; ++m)
      afr[m] = *(const short8*)&As[(wm * 64 + m * 16 + fr) * 32 + fk * 8];
#pragma unroll
    for (int n = 0; n < NF; ++n)
      bfr[n] = *(const short8*)&Bs[(wn * (BN / 2) + n * 16 + fr) * 32 + fk * 8];
#pragma unroll
    for (int m = 0; m < 4; ++m)
#pragma unroll
      for (int n = 0; n < NF; ++n) acc[m][n] = mfma16(afr[m], bfr[n], acc[m][n]);
    __syncthreads();
  }

  const int cc = lane & 15, cr = (lane >> 4) * 4;
#pragma unroll
  for (int m = 0; m < 4; ++m)
#pragma unroll
    for (int n = 0; n < NF; ++n)
#pragma unroll
      for (int j = 0; j < 4; ++j) {
        size_t row = m0 + wm * 64 + m * 16 + cr + j;
        size_t col = n0 + wn * (BN / 2) + n * 16 + cc;
        float v = acc[m][n][j];
        if constexpr (EPI == 0) {
          if (col < DINNER) outh0[row * DINNER + col] = f2bf(v);
          else outh1[row * DINNER + (col - DINNER)] = f2bf(v);
        } else if constexpr (EPI == 1) {
          outf[row * 64 + col] = v;
        } else if constexpr (EPI == 2) {
          outf[row * (size_t)N + col] = aux[row * (size_t)N + col] + v;
        } else if constexpr (EPI == 3) {
          float t = v + aux[col];
          float g = 0.5f * t * (1.f + erff(t * 0.70710678118654752f));
          outh0[row * (size_t)N + col] = f2bf(g);
        } else if constexpr (EPI == 4) {
          outf[row * (size_t)N + col] += v + aux[col];
        }
      }
}

// ---------------- depthwise causal conv(4) + bias + silu, bf16 in/out ----------------
__global__ __launch_bounds__(256) void k_conv(const u16* __restrict__ upre,
                                              const float* __restrict__ cw,
                                              const float* __restrict__ cb,
                                              u16* __restrict__ u) {
  int tid = threadIdx.x;
  int d = blockIdx.x * 256 + tid;
  int l0 = blockIdx.y * 16;
  int b = blockIdx.z;
  size_t tokbase = (size_t)b * LSEQ;
  float s[19];
#pragma unroll
  for (int r = 0; r < 19; ++r) {
    int gl = l0 - 3 + r;
    s[r] = (gl >= 0) ? bf2f(upre[(tokbase + gl) * DINNER + d]) : 0.f;
  }
  float w0 = cw[d * 4 + 0], w1 = cw[d * 4 + 1], w2 = cw[d * 4 + 2], w3 = cw[d * 4 + 3];
  float bias = cb[d];
#pragma unroll
  for (int i = 0; i < 16; ++i) {
    float a = bias + w0 * s[i] + w1 * s[i + 1] + w2 * s[i + 2] + w3 * s[i + 3];
    float sig = 1.f / (1.f + __expf(-a));
    u[(tokbase + l0 + i) * DINNER + d] = f2bf(a * sig);
  }
}

// ---------------- dt_proj + softplus -> delta (bf16) ----------------
__global__ __launch_bounds__(256) void k_dtproj(const float* __restrict__ xdbl,
                                                const u16* __restrict__ wdt,
                                                const float* __restrict__ bdt,
                                                u16* __restrict__ delta) {
  __shared__ __align__(16) u16 wsm[768 * 24];
  __shared__ __align__(16) float dts[32][24];
  int tid = threadIdx.x;
  for (int i = tid; i < 768 * 24; i += 256) wsm[i] = wdt[i];
  int tok0 = blockIdx.x * 32;
  for (int i = tid; i < 32 * 24; i += 256) {
    int t = i / 24, r = i - t * 24;
    dts[t][r] = xdbl[(size_t)(tok0 + t) * 64 + r];
  }
  __syncthreads();
  for (int dd = 0; dd < 3; ++dd) {
    int d = dd * 256 + tid;
    float wreg[24];
#pragma unroll
    for (int r = 0; r < 24; ++r) wreg[r] = bf2f(wsm[d * 24 + r]);
    float bias = bdt[d];
    for (int t = 0; t < 32; ++t) {
      float acc = bias;
#pragma unroll
      for (int r = 0; r < 24; ++r) acc = fmaf(dts[t][r], wreg[r], acc);
      float sp = (acc > 20.f) ? acc : log1pf(__expf(acc));
      delta[(size_t)(tok0 + t) * DINNER + d] = f2bf(sp);
    }
  }
}

// ---------------- chunked selective scan ----------------
// Decomposition: h_t = dA_t h_{t-1} + x_t.  Over a chunk, h_end = P*h_start + h_zero
// with P = prod(dA) = exp2(A2 * sum(delta)).  Pass A computes (h_zero_end, P) per
// chunk from h=0; pass B combines across chunks; pass C rescans with true h_start
// and produces the gated output.
// Block = one (batch, 16-channel group, chunk); lane = (channel, state):
// ch = (wave<<2)|(lane>>4), s = lane&15 -> the 16 state lanes are one DPP row.

// pass A: per-chunk (h_final, P)
__global__ __launch_bounds__(256) void k_scan_a(
    const u16* __restrict__ delta, const u16* __restrict__ u,
    const float* __restrict__ xdbl, const float* __restrict__ A_log,
    float* __restrict__ hfin, float* __restrict__ Pp) {
  __shared__ float sdT[16][68];  // [ch][t], stride 68 -> 16B-aligned rows, no 4-way conflicts
  __shared__ float suT[16][68];
  __shared__ float sBT[16][68];  // [s][t]
  int bid = blockIdx.x;
  int dg = bid % 48;
  int c = (bid / 48) % NC;
  int b = bid / (48 * NC);
  int d0 = dg * 16;
  int tid = threadIdx.x, lane = tid & 63, w = tid >> 6;
  int chL = (w << 2) | (lane >> 4);
  int s = lane & 15;
  int d = d0 + chL;
  float A2 = -__expf(A_log[d * 16 + s]) * 1.44269504f;  // A * log2(e)
  float h = 0.f, S = 0.f;
  int le = tid >> 2, je = (tid & 3) << 2;
  size_t tb = (size_t)b * LSEQ + (size_t)c * CHUNK;

  ushort4 dv, uv;
  float4 Bv;
  {  // stage sub-chunk 0
    size_t tok = tb + le;
    dv = *(const ushort4*)&delta[tok * DINNER + d0 + je];
    uv = *(const ushort4*)&u[tok * DINNER + d0 + je];
    Bv = *(const float4*)&xdbl[tok * 64 + 24 + je];
    sdT[je + 0][le] = bf2f(dv.x); sdT[je + 1][le] = bf2f(dv.y);
    sdT[je + 2][le] = bf2f(dv.z); sdT[je + 3][le] = bf2f(dv.w);
    suT[je + 0][le] = bf2f(uv.x); suT[je + 1][le] = bf2f(uv.y);
    suT[je + 2][le] = bf2f(uv.z); suT[je + 3][le] = bf2f(uv.w);
    sBT[je + 0][le] = Bv.x; sBT[je + 1][le] = Bv.y;
    sBT[je + 2][le] = Bv.z; sBT[je + 3][le] = Bv.w;
  }
  for (int sc = 0; sc < CHUNK / SUB; ++sc) {
    bool more = (sc + 1) < CHUNK / SUB;
    if (more) {
      size_t tok = tb + (sc + 1) * SUB + le;
      dv = *(const ushort4*)&delta[tok * DINNER + d0 + je];
      uv = *(const ushort4*)&u[tok * DINNER + d0 + je];
      Bv = *(const float4*)&xdbl[tok * 64 + 24 + je];
    }
    __syncthreads();
    for (int t4 = 0; t4 < SUB; t4 += 4) {
      float4 dq = *(const float4*)&sdT[chL][t4];
      float4 uq = *(const float4*)&suT[chL][t4];
      float4 Bq = *(const float4*)&sBT[s][t4];
#pragma unroll
      for (int j = 0; j < 4; ++j) {
        float dvx = dq[j];
        float dA = exp2f(dvx * A2);
        S += dvx;
        h = fmaf(dA, h, dvx * uq[j] * Bq[j]);
      }
    }
    __syncthreads();
    if (more) {
      sdT[je + 0][le] = bf2f(dv.x); sdT[je + 1][le] = bf2f(dv.y);
      sdT[je + 2][le] = bf2f(dv.z); sdT[je + 3][le] = bf2f(dv.w);
      suT[je + 0][le] = bf2f(uv.x); suT[je + 1][le] = bf2f(uv.y);
      suT[je + 2][le] = bf2f(uv.z); suT[je + 3][le] = bf2f(uv.w);
      sBT[je + 0][le] = Bv.x; sBT[je + 1][le] = Bv.y;
      sBT[je + 2][le] = Bv.z; sBT[je + 3][le] = Bv.w;
    }
  }
  size_t o = (((size_t)b * NC + c) * DINNER + d) * 16 + s;  // = base + lane (coalesced)
  hfin[o] = h;
  Pp[o] = exp2f(A2 * S);
}

// pass B: sequential combine across NC chunks -> per-chunk start states
__global__ __launch_bounds__(256) void k_fixup(const float* __restrict__ hfin,
                                               const float* __restrict__ Pp,
                                               float* __restrict__ Hs) {
  int i = blockIdx.x * 256 + threadIdx.x;  // over NBATCH*DINNER*16
  int b = i / (DINNER * 16);
  int rem = i - b * (DINNER * 16);
  float H = 0.f;
#pragma unroll
  for (int c = 0; c < NC; ++c) {
    size_t o = ((size_t)b * NC + c) * (DINNER * 16) + rem;
    Hs[o] = H;
    H = Pp[o] * H + hfin[o];
  }
}

// pass C: rescan with true start state; y = (scan + u*D) * silu(z), bf16 out
__global__ __launch_bounds__(256) void k_scan_c(
    const u16* __restrict__ delta, const u16* __restrict__ u,
    const float* __restrict__ xdbl, const u16* __restrict__ z,
    const float* __restrict__ A_log, const float* __restrict__ Dvec,
    const float* __restrict__ Hs, u16* __restrict__ y) {
  __shared__ float sdT[16][68];
  __shared__ float suT[16][68];
  __shared__ float szT[16][68];
  __shared__ float sBT[16][68];
  __shared__ float sCT[16][68];
  __shared__ u16 syT[16][68];
  int bid = blockIdx.x;
  int dg = bid % 48;
  int c = (bid / 48) % NC;
  int b = bid / (48 * NC);
  int d0 = dg * 16;
  int tid = threadIdx.x, lane = tid & 63, w = tid >> 6;
  int chL = (w << 2) | (lane >> 4);
  int s = lane & 15;
  int d = d0 + chL;
  float A2 = -__expf(A_log[d * 16 + s]) * 1.44269504f;
  float Dd = Dvec[d];
  float h = Hs[(((size_t)b * NC + c) * DINNER + d) * 16 + s];
  int le = tid >> 2, je = (tid & 3) << 2;
  size_t tb = (size_t)b * LSEQ + (size_t)c * CHUNK;

  ushort4 dv, uv, zv;
  float4 Bv, Cv;
  {  // stage sub-chunk 0
    size_t tok = tb + le;
    dv = *(const ushort4*)&delta[tok * DINNER + d0 + je];
    uv = *(const ushort4*)&u[tok * DINNER + d0 + je];
    zv = *(const ushort4*)&z[tok * DINNER + d0 + je];
    Bv = *(const float4*)&xdbl[tok * 64 + 24 + je];
    Cv = *(const float4*)&xdbl[tok * 64 + 40 + je];
    sdT[je + 0][le] = bf2f(dv.x); sdT[je + 1][le] = bf2f(dv.y);
    sdT[je + 2][le] = bf2f(dv.z); sdT[je + 3][le] = bf2f(dv.w);
    suT[je + 0][le] = bf2f(uv.x); suT[je + 1][le] = bf2f(uv.y);
    suT[je + 2][le] = bf2f(uv.z); suT[je + 3][le] = bf2f(uv.w);
    szT[je + 0][le] = bf2f(zv.x); szT[je + 1][le] = bf2f(zv.y);
    szT[je + 2][le] = bf2f(zv.z); szT[je + 3][le] = bf2f(zv.w);
    sBT[je + 0][le] = Bv.x; sBT[je + 1][le] = Bv.y;
    sBT[je + 2][le] = Bv.z; sBT[je + 3][le] = Bv.w;
    sCT[je + 0][le] = Cv.x; sCT[je + 1][le] = Cv.y;
    sCT[je + 2][le] = Cv.z; sCT[je + 3][le] = Cv.w;
  }
  for (int sc = 0; sc < CHUNK / SUB; ++sc) {
    bool more = (sc + 1) < CHUNK / SUB;
    if (more) {
      size_t tok = tb + (sc + 1) * SUB + le;
      dv = *(const ushort4*)&delta[tok * DINNER + d0 + je];
      uv = *(const ushort4*)&u[tok * DINNER + d0 + je];
      zv = *(const ushort4*)&z[tok * DINNER + d0 + je];
      Bv = *(const float4*)&xdbl[tok * 64 + 24 + je];
      Cv = *(const float4*)&xdbl[tok * 64 + 40 + je];
    }
    __syncthreads();
    for (int t4 = 0; t4 < SUB; t4 += 4) {
      float4 dq = *(const float4*)&sdT[chL][t4];
      float4 uq = *(const float4*)&suT[chL][t4];
      float4 zq = *(const float4*)&szT[chL][t4];
      float4 Bq = *(const float4*)&sBT[s][t4];
      float4 Cq = *(const float4*)&sCT[s][t4];
      ushort4 pk;
#pragma unroll
      for (int j = 0; j < 4; ++j) {
        float dvx = dq[j], uvx = uq[j];
        float dA = exp2f(dvx * A2);
        h = fmaf(dA, h, dvx * uvx * Bq[j]);
        float yc = row16_sum(h * Cq[j]);  // sum over 16 states, VALU-only DPP
        float zvx = zq[j];
        float sig = 1.f / (1.f + exp2f(zvx * -1.44269504f));
        u16 r = f2bf((yc + uvx * Dd) * (zvx * sig));
        if (j == 0) pk.x = r;
        else if (j == 1) pk.y = r;
        else if (j == 2) pk.z = r;
        else pk.w = r;
      }
      if (s == 0) *(ushort4*)&syT[chL][t4] = pk;
    }
    __syncthreads();
    {  // flush 64 x 16 outputs, coalesced
      int t = tid >> 2;
      size_t tok = tb + sc * SUB + t;
      ushort4 o;
      o.x = syT[je + 0][t]; o.y = syT[je + 1][t];
      o.z = syT[je + 2][t]; o.w = syT[je + 3][t];
      *(ushort4*)&y[tok * DINNER + d0 + je] = o;
    }
    if (more) {
      sdT[je + 0][le] = bf2f(dv.x); sdT[je + 1][le] = bf2f(dv.y);
      sdT[je + 2][le] = bf2f(dv.z); sdT[je + 3][le] = bf2f(dv.w);
      suT[je + 0][le] = bf2f(uv.x); suT[je + 1][le] = bf2f(uv.y);
      suT[je + 2][le] = bf2f(uv.z); suT[je + 3][le] = bf2f(uv.w);
      szT[je + 0][le] = bf2f(zv.x); szT[je + 1][le] = bf2f(zv.y);
      szT[je + 2][le] = bf2f(zv.z); szT[je + 3][le] = bf2f(zv.w);
      sBT[je + 0][le] = Bv.x; sBT[je + 1][le] = Bv.y;
      sBT[je + 2][le] = Bv.z; sBT[je + 3][le] = Bv.w;
      sCT[je + 0][le] = Cv.x; sCT[je + 1][le] = Cv.y;
      sCT[je + 2][le] = Cv.z; sCT[je + 3][le] = Cv.w;
    }
  }
}

// ---------------- launch ----------------
// Workspace budget ~190 MiB (round-8 passed at 180; +9.4MB scan-chunk state):
//   x1n 25MB (also x2n) | upre 48MB (also delta bf16) | u 48MB (also h1 lo)
//   y 48MB (also h1 hi) | xdbl 8MB | hfin/Pp/Hs 3.1MB each | weights ~4.3MB
//   z -> lives in d_out (dead before out_proj overwrites d_out)
extern "C" void kernel_launch(void* const* d_in, const int* in_sizes, int n_in,
                              void* d_out, int out_size, void* d_ws, size_t ws_size,
                              hipStream_t stream) {
  (void)in_sizes; (void)n_in; (void)out_size; (void)ws_size;
  const float* x       = (const float*)d_in[0];
  const float* norm1_w = (const float*)d_in[1];
  const float* w_in    = (const float*)d_in[2];
  const float* conv_w  = (const float*)d_in[3];
  const float* conv_b  = (const float*)d_in[4];
  const float* w_xproj = (const float*)d_in[5];
  const float* w_dt    = (const float*)d_in[6];
  const float* b_dt    = (const float*)d_in[7];
  const float* A_log   = (const float*)d_in[8];
  const float* Dv      = (const float*)d_in[9];
  const float* w_out   = (const float*)d_in[10];
  const float* norm2_w = (const float*)d_in[11];
  const float* fc1_w   = (const float*)d_in[12];
  const float* fc1_b   = (const float*)d_in[13];
  const float* fc2_w   = (const float*)d_in[14];
  const float* fc2_b   = (const float*)d_in[15];
  float* out = (float*)d_out;

  char* ws = (char*)d_ws;
  size_t off = 0;
  auto alloc = [&](size_t bytes) {
    char* p = ws + off;
    off += (bytes + 255) & ~(size_t)255;
    return p;
  };
  u16* x1n    = (u16*)alloc((size_t)TOKENS * DMODEL * 2);   // also x2n
  u16* upre   = (u16*)alloc((size_t)TOKENS * DINNER * 2);   // also delta (bf16)
  u16* u      = (u16*)alloc((size_t)TOKENS * DINNER * 2);   // also h1[:, :768]
  u16* y      = (u16*)alloc((size_t)TOKENS * DINNER * 2);   // also h1[:, 768:]
  float* xdbl = (float*)alloc((size_t)TOKENS * 64 * 4);
  float* hfin = (float*)alloc((size_t)NBATCH * NC * DINNER * 16 * 4);
  float* Pp   = (float*)alloc((size_t)NBATCH * NC * DINNER * 16 * 4);
  float* Hs   = (float*)alloc((size_t)NBATCH * NC * DINNER * 16 * 4);
  u16* w_in_h = (u16*)alloc((size_t)1536 * 384 * 2);
  u16* wxp_h  = (u16*)alloc((size_t)64 * 768 * 2);
  u16* wdt_h  = (u16*)alloc((size_t)768 * 24 * 2);
  u16* w_out_h= (u16*)alloc((size_t)384 * 768 * 2);
  u16* fc1_h  = (u16*)alloc((size_t)1536 * 384 * 2);
  u16* fc2_h  = (u16*)alloc((size_t)384 * 1536 * 2);
  u16* z      = (u16*)d_out;  // 32768*768*2 B == 32768*384*4 B exactly
  u16* delta_h = upre;        // upre dead after conv
  u16* h1 = u;                // u (dead after scan) ∥ y (dead after out_proj)
  u16* x2n = x1n;             // x1n dead after in_proj

  // weight conversions (each call; ws is re-poisoned every launch)
  k_f2bf<<<256, 256, 0, stream>>>(w_in, w_in_h, 1536 * 384);
  k_pad_wxp<<<(64 * 768 + 255) / 256, 256, 0, stream>>>(w_xproj, wxp_h);
  k_f2bf<<<72, 256, 0, stream>>>(w_dt, wdt_h, 768 * 24);
  k_f2bf<<<256, 256, 0, stream>>>(w_out, w_out_h, 384 * 768);
  k_f2bf<<<256, 256, 0, stream>>>(fc1_w, fc1_h, 1536 * 384);
  k_f2bf<<<256, 256, 0, stream>>>(fc2_w, fc2_h, 384 * 1536);

  // 1) rmsnorm1
  k_rmsnorm<<<TOKENS / 4, 256, 0, stream>>>(x, norm1_w, x1n);
  // 2) in_proj -> u_pre, z(in d_out)
  k_gemm_bt<128, 0><<<256 * 12, 256, 0, stream>>>(x1n, w_in_h, 384, 1536, 256,
                                                  nullptr, nullptr, upre, z);
  // 3) conv + silu -> u
  dim3 cgrid(3, 256, 8);
  k_conv<<<cgrid, 256, 0, stream>>>(upre, conv_w, conv_b, u);
  // 4) x_proj -> xdbl (padded stride 64)
  k_gemm_bt<64, 1><<<256 * 1, 256, 0, stream>>>(u, wxp_h, 768, 64, 256,
                                                nullptr, xdbl, nullptr, nullptr);
  // 5) dt_proj + softplus -> delta (bf16, in upre region)
  k_dtproj<<<TOKENS / 32, 256, 0, stream>>>(xdbl, wdt_h, b_dt, delta_h);
  // 6) chunked selective scan -> y
  k_scan_a<<<NBATCH * NC * 48, 256, 0, stream>>>(delta_h, u, xdbl, A_log, hfin, Pp);
  k_fixup<<<NBATCH * DINNER * 16 / 256, 256, 0, stream>>>(hfin, Pp, Hs);
  k_scan_c<<<NBATCH * NC * 48, 256, 0, stream>>>(delta_h, u, xdbl, z, A_log, Dv, Hs, y);
  // 7) out_proj + residual -> d_out (= x2); overwrites z region
  k_gemm_bt<128, 2><<<256 * 3, 256, 0, stream>>>(y, w_out_h, 768, 384, 256,
                                                 x, out, nullptr, nullptr);
  // 8) rmsnorm2
  k_rmsnorm<<<TOKENS / 4, 256, 0, stream>>>(out, norm2_w, x2n);
  // 9) fc1 + gelu -> h1 (over u∥y)
  k_gemm_bt<128, 3><<<256 * 12, 256, 0, stream>>>(x2n, fc1_h, 384, 1536, 256,
                                                  fc1_b, nullptr, h1, nullptr);
  // 10) fc2 + bias + residual -> d_out
  k_gemm_bt<128, 4><<<256 * 3, 256, 0, stream>>>(h1, fc2_h, 1536, 384, 256,
                                                 fc2_b, out, nullptr, nullptr);
}

// Round 11
// 857.453 us; speedup vs baseline: 1.9025x; 1.3712x over previous
//
#include <hip/hip_runtime.h>
#include <cstdint>
#include <cstddef>

typedef unsigned short u16;
typedef short short8 __attribute__((ext_vector_type(8)));
typedef __bf16 bf16x8 __attribute__((ext_vector_type(8)));
typedef float f32x4 __attribute__((ext_vector_type(4)));

#define TOKENS 32768
#define DMODEL 384
#define DINNER 768
#define HIDDEN_DIM 1536
#define LSEQ 4096
#define NBATCH 8
#define NC 32          // scan chunks per sequence
#define CHUNK 128      // LSEQ / NC
#define SUB 32         // timesteps staged per LDS round

__device__ __forceinline__ float bf2f(u16 h) {
  return __uint_as_float(((unsigned)h) << 16);
}
__device__ __forceinline__ u16 f2bf(float f) {
  unsigned x = __float_as_uint(f);
  unsigned r = x + 0x7fffu + ((x >> 16) & 1u);
  return (u16)(r >> 16);
}

__device__ __forceinline__ void gload_lds16(const void* g, void* l) {
  __builtin_amdgcn_global_load_lds(
      (const __attribute__((address_space(1))) unsigned int*)g,
      (__attribute__((address_space(3))) unsigned int*)l, 16, 0, 0);
}

__device__ __forceinline__ f32x4 mfma16(short8 a, short8 b, f32x4 c) {
  return __builtin_amdgcn_mfma_f32_16x16x32_bf16(
      __builtin_bit_cast(bf16x8, a), __builtin_bit_cast(bf16x8, b), c, 0, 0, 0);
}

// ---------------- weight conversion ----------------
__global__ void k_f2bf(const float* __restrict__ in, u16* __restrict__ out, int n) {
  int i = blockIdx.x * 256 + threadIdx.x;
  int stride = gridDim.x * 256;
  for (; i < n; i += stride) out[i] = f2bf(in[i]);
}

// pad w_xproj (56x768) -> (64x768) bf16, rows 56..63 zero
__global__ void k_pad_wxp(const float* __restrict__ in, u16* __restrict__ out) {
  int i = blockIdx.x * 256 + threadIdx.x;
  if (i >= 64 * 768) return;
  int r = i / 768, c = i - r * 768;
  out[i] = (r < 56) ? f2bf(in[r * 768 + c]) : (u16)0;
}

// A2t[s][d] = -exp(A_log[d][s]) * log2(e)  (transposed for coalesced lane loads)
__global__ void k_prepA(const float* __restrict__ A_log, float* __restrict__ A2t) {
  int i = blockIdx.x * 256 + threadIdx.x;
  if (i >= DINNER * 16) return;
  int d = i >> 4, s = i & 15;
  A2t[s * DINNER + d] = -__expf(A_log[i]) * 1.44269504f;
}

// ---------------- rmsnorm (f32 in -> bf16 out), 1 wave per token ----------------
__global__ __launch_bounds__(256) void k_rmsnorm(const float* __restrict__ x,
                                                 const float* __restrict__ w,
                                                 u16* __restrict__ out) {
  int lane = threadIdx.x & 63;
  size_t tok = (size_t)blockIdx.x * 4 + (threadIdx.x >> 6);
  const float* xr = x + tok * DMODEL;
  float v[6];
  float ss = 0.f;
#pragma unroll
  for (int i = 0; i < 6; ++i) {
    v[i] = xr[lane + 64 * i];
    ss = fmaf(v[i], v[i], ss);
  }
#pragma unroll
  for (int off = 32; off; off >>= 1) ss += __shfl_xor(ss, off);
  float sc = rsqrtf(ss * (1.f / (float)DMODEL) + 1e-5f);
  u16* orow = out + tok * DMODEL;
#pragma unroll
  for (int i = 0; i < 6; ++i) orow[lane + 64 * i] = f2bf(v[i] * sc * w[lane + 64 * i]);
}

// ---------------- GEMM: C[M,N] = A[M,K](bf16) @ Bt[N,K](bf16)^T, epilogues ----------------
template <int BN, int EPI>
__global__ __launch_bounds__(256) void k_gemm_bt(
    const u16* __restrict__ A, const u16* __restrict__ Bt, int K, int N, int gridM,
    const float* __restrict__ aux, float* __restrict__ outf,
    u16* __restrict__ outh0, u16* __restrict__ outh1) {
  static_assert(BN == 64 || BN == 128, "BN");
  constexpr int NF = BN / 32;
  __shared__ __align__(16) u16 As[128 * 32];
  __shared__ __align__(16) u16 Bs[BN * 32];
  const int tid = threadIdx.x;
  const int lane = tid & 63;
  const int w = tid >> 6;
  const int wm = w >> 1, wn = w & 1;
  const int mb = blockIdx.x % gridM;
  const int nb = blockIdx.x / gridM;
  const size_t m0 = (size_t)mb * 128, n0 = (size_t)nb * BN;

  f32x4 acc[4][NF];
#pragma unroll
  for (int m = 0; m < 4; ++m)
#pragma unroll
    for (int n = 0; n < NF; ++n) acc[m][n] = (f32x4){0.f, 0.f, 0.f, 0.f};

  const int r4 = tid >> 2, c4 = tid & 3;
  const u16* ga = A + (m0 + r4) * (size_t)K + c4 * 8;
  const u16* gb = Bt + (n0 + r4) * (size_t)K + c4 * 8;
  const int fr = lane & 15, fk = lane >> 4;

  for (int kt = 0; kt < K; kt += 32) {
    gload_lds16(ga + kt, &As[tid * 8]);
    gload_lds16(ga + (size_t)64 * K + kt, &As[2048 + tid * 8]);
    gload_lds16(gb + kt, &Bs[tid * 8]);
    if constexpr (BN == 128) gload_lds16(gb + (size_t)64 * K + kt, &Bs[2048 + tid * 8]);
    __syncthreads();
    short8 afr[4], bfr[NF];
#pragma unroll
    for (int m = 0; m < 4; ++m)
      afr[m] = *(const short8*)&As[(wm * 64 + m * 16 + fr) * 32 + fk * 8];
#pragma unroll
    for (int n = 0; n < NF; ++n)
      bfr[n] = *(const short8*)&Bs[(wn * (BN / 2) + n * 16 + fr) * 32 + fk * 8];
#pragma unroll
    for (int m = 0; m < 4; ++m)
#pragma unroll
      for (int n = 0; n < NF; ++n) acc[m][n] = mfma16(afr[m], bfr[n], acc[m][n]);
    __syncthreads();
  }

  const int cc = lane & 15, cr = (lane >> 4) * 4;
#pragma unroll
  for (int m = 0; m < 4; ++m)
#pragma unroll
    for (int n = 0; n < NF; ++n)
#pragma unroll
      for (int j = 0; j < 4; ++j) {
        size_t row = m0 + wm * 64 + m * 16 + cr + j;
        size_t col = n0 + wn * (BN / 2) + n * 16 + cc;
        float v = acc[m][n][j];
        if constexpr (EPI == 0) {
          if (col < DINNER) outh0[row * DINNER + col] = f2bf(v);
          else outh1[row * DINNER + (col - DINNER)] = f2bf(v);
        } else if constexpr (EPI == 1) {
          outf[row * 64 + col] = v;
        } else if constexpr (EPI == 2) {
          outf[row * (size_t)N + col] = aux[row * (size_t)N + col] + v;
        } else if constexpr (EPI == 3) {
          float t = v + aux[col];
          float g = 0.5f * t * (1.f + erff(t * 0.70710678118654752f));
          outh0[row * (size_t)N + col] = f2bf(g);
        } else if constexpr (EPI == 4) {
          outf[row * (size_t)N + col] += v + aux[col];
        }
      }
}

// ---------------- depthwise causal conv(4) + bias + silu, bf16 in/out ----------------
__global__ __launch_bounds__(256) void k_conv(const u16* __restrict__ upre,
                                              const float* __restrict__ cw,
                                              const float* __restrict__ cb,
                                              u16* __restrict__ u) {
  int tid = threadIdx.x;
  int d = blockIdx.x * 256 + tid;
  int l0 = blockIdx.y * 16;
  int b = blockIdx.z;
  size_t tokbase = (size_t)b * LSEQ;
  float s[19];
#pragma unroll
  for (int r = 0; r < 19; ++r) {
    int gl = l0 - 3 + r;
    s[r] = (gl >= 0) ? bf2f(upre[(tokbase + gl) * DINNER + d]) : 0.f;
  }
  float w0 = cw[d * 4 + 0], w1 = cw[d * 4 + 1], w2 = cw[d * 4 + 2], w3 = cw[d * 4 + 3];
  float bias = cb[d];
#pragma unroll
  for (int i = 0; i < 16; ++i) {
    float a = bias + w0 * s[i] + w1 * s[i + 1] + w2 * s[i + 2] + w3 * s[i + 3];
    float sig = 1.f / (1.f + __expf(-a));
    u[(tokbase + l0 + i) * DINNER + d] = f2bf(a * sig);
  }
}

// ---------------- dt_proj + softplus -> delta (bf16) ----------------
__global__ __launch_bounds__(256) void k_dtproj(const float* __restrict__ xdbl,
                                                const u16* __restrict__ wdt,
                                                const float* __restrict__ bdt,
                                                u16* __restrict__ delta) {
  __shared__ __align__(16) u16 wsm[768 * 24];
  __shared__ __align__(16) float dts[32][24];
  int tid = threadIdx.x;
  for (int i = tid; i < 768 * 24; i += 256) wsm[i] = wdt[i];
  int tok0 = blockIdx.x * 32;
  for (int i = tid; i < 32 * 24; i += 256) {
    int t = i / 24, r = i - t * 24;
    dts[t][r] = xdbl[(size_t)(tok0 + t) * 64 + r];
  }
  __syncthreads();
  for (int dd = 0; dd < 3; ++dd) {
    int d = dd * 256 + tid;
    float wreg[24];
#pragma unroll
    for (int r = 0; r < 24; ++r) wreg[r] = bf2f(wsm[d * 24 + r]);
    float bias = bdt[d];
    for (int t = 0; t < 32; ++t) {
      float acc = bias;
#pragma unroll
      for (int r = 0; r < 24; ++r) acc = fmaf(dts[t][r], wreg[r], acc);
      float sp = (acc > 20.f) ? acc : log1pf(__expf(acc));
      delta[(size_t)(tok0 + t) * DINNER + d] = f2bf(sp);
    }
  }
}

// ---------------- chunked selective scan, one channel per lane ----------------
// Lane owns channel d = g*256 + tid with all 16 states in registers.
// Per timestep: 16x {mul,exp2,fma} state update + 16 fma y-reduction; B/C are
// LDS broadcasts; no cross-lane ops.  Chunk decomposition as round 9:
// h_end = P*h_start + h_zero, P_s = exp2(A2_s * sum(delta)).

// pass A: per-chunk (h_zero_final, P) from h=0
__global__ __launch_bounds__(256) void k_scan_a(
    const u16* __restrict__ delta, const u16* __restrict__ u,
    const float* __restrict__ xdbl, const float* __restrict__ A2t,
    float* __restrict__ hfin, float* __restrict__ Pp) {
  __shared__ __align__(16) u16 sd[SUB * 256];
  __shared__ __align__(16) u16 su[SUB * 256];
  __shared__ __align__(16) float sB[SUB * 16];
  int bid = blockIdx.x;
  int g = bid % 3;
  int c = (bid / 3) % NC;
  int b = bid / (3 * NC);
  int d0 = g * 256;
  int tid = threadIdx.x;
  int w = tid >> 6, l = tid & 63;
  int d = d0 + tid;
  float A2[16], h[16];
#pragma unroll
  for (int s = 0; s < 16; ++s) { A2[s] = A2t[s * DINNER + d]; h[s] = 0.f; }
  float S = 0.f;
  size_t tb = (size_t)b * LSEQ + (size_t)c * CHUNK;
  const int r0 = l >> 5, ccol = (l & 31) * 8;

  for (int sc = 0; sc < CHUNK / SUB; ++sc) {
    size_t t0 = tb + sc * SUB;
    // stage: each wave covers rows [8w, 8w+8) of the [32][256] bf16 tiles
#pragma unroll
    for (int k = 0; k < 4; ++k) {
      int r = 8 * w + 2 * k;
      gload_lds16(&delta[(t0 + r + r0) * DINNER + d0 + ccol], &sd[r * 256]);
      gload_lds16(&u[(t0 + r + r0) * DINNER + d0 + ccol], &su[r * 256]);
    }
    if (w < 2)  // B tile [32][16] f32: wave w covers rows [16w, 16w+16)
      gload_lds16(&xdbl[(t0 + w * 16 + (l >> 2)) * 64 + 24 + (l & 3) * 4],
                  &sB[w * 256]);
    __syncthreads();
#pragma unroll 2
    for (int t = 0; t < SUB; ++t) {
      float dvx = bf2f(sd[t * 256 + tid]);
      float uvx = bf2f(su[t * 256 + tid]);
      float du = dvx * uvx;
      S += dvx;
      const float4* Bp = (const float4*)&sB[t * 16];
#pragma unroll
      for (int q = 0; q < 4; ++q) {
        float4 Bq = Bp[q];
#pragma unroll
        for (int j = 0; j < 4; ++j) {
          int s = q * 4 + j;
          float dA = exp2f(dvx * A2[s]);
          h[s] = fmaf(dA, h[s], du * Bq[j]);
        }
      }
    }
    __syncthreads();
  }
  size_t o = ((size_t)(b * NC + c) * 16) * DINNER + d;  // layout [bc][s][d]
#pragma unroll
  for (int s = 0; s < 16; ++s) {
    hfin[o + s * DINNER] = h[s];
    Pp[o + s * DINNER] = exp2f(A2[s] * S);
  }
}

// pass B: in-place sequential combine; hfin becomes the chunk START state
__global__ __launch_bounds__(256) void k_fixup(float* __restrict__ hfin,
                                               const float* __restrict__ Pp) {
  int i = blockIdx.x * 256 + threadIdx.x;  // over NBATCH * 16 * DINNER
  int b = i / (16 * DINNER);
  int rem = i - b * (16 * DINNER);
  size_t base = (size_t)b * NC * (16 * DINNER) + rem;
  float H = 0.f;
#pragma unroll
  for (int c = 0; c < NC; ++c) {
    size_t o = base + (size_t)c * (16 * DINNER);
    float hf = hfin[o];
    float P = Pp[o];
    hfin[o] = H;
    H = fmaf(P, H, hf);
  }
}

// pass C: rescan with true start state; y = (scan + u*D) * silu(z), bf16 out
__global__ __launch_bounds__(256) void k_scan_c(
    const u16* __restrict__ delta, const u16* __restrict__ u,
    const float* __restrict__ xdbl, const u16* __restrict__ z,
    const float* __restrict__ A2t, const float* __restrict__ Dvec,
    const float* __restrict__ Hs, u16* __restrict__ y) {
  __shared__ __align__(16) u16 sd[SUB * 256];
  __shared__ __align__(16) u16 su[SUB * 256];
  __shared__ __align__(16) u16 sz[SUB * 256];
  __shared__ __align__(16) float sB[SUB * 16];
  __shared__ __align__(16) float sC[SUB * 16];
  int bid = blockIdx.x;
  int g = bid % 3;
  int c = (bid / 3) % NC;
  int b = bid / (3 * NC);
  int d0 = g * 256;
  int tid = threadIdx.x;
  int w = tid >> 6, l = tid & 63;
  int d = d0 + tid;
  float A2[16], h[16];
  size_t o0 = ((size_t)(b * NC + c) * 16) * DINNER + d;
#pragma unroll
  for (int s = 0; s < 16; ++s) {
    A2[s] = A2t[s * DINNER + d];
    h[s] = Hs[o0 + s * DINNER];
  }
  float Dd = Dvec[d];
  size_t tb = (size_t)b * LSEQ + (size_t)c * CHUNK;
  const int r0 = l >> 5, ccol = (l & 31) * 8;

  for (int sc = 0; sc < CHUNK / SUB; ++sc) {
    size_t t0 = tb + sc * SUB;
#pragma unroll
    for (int k = 0; k < 4; ++k) {
      int r = 8 * w + 2 * k;
      gload_lds16(&delta[(t0 + r + r0) * DINNER + d0 + ccol], &sd[r * 256]);
      gload_lds16(&u[(t0 + r + r0) * DINNER + d0 + ccol], &su[r * 256]);
      gload_lds16(&z[(t0 + r + r0) * DINNER + d0 + ccol], &sz[r * 256]);
    }
    if (w < 2)
      gload_lds16(&xdbl[(t0 + w * 16 + (l >> 2)) * 64 + 24 + (l & 3) * 4],
                  &sB[w * 256]);
    else
      gload_lds16(&xdbl[(t0 + (w - 2) * 16 + (l >> 2)) * 64 + 40 + (l & 3) * 4],
                  &sC[(w - 2) * 256]);
    __syncthreads();
#pragma unroll 2
    for (int t = 0; t < SUB; ++t) {
      float dvx = bf2f(sd[t * 256 + tid]);
      float uvx = bf2f(su[t * 256 + tid]);
      float zvx = bf2f(sz[t * 256 + tid]);
      float du = dvx * uvx;
      float yacc = 0.f;
      const float4* Bp = (const float4*)&sB[t * 16];
      const float4* Cp = (const float4*)&sC[t * 16];
#pragma unroll
      for (int q = 0; q < 4; ++q) {
        float4 Bq = Bp[q];
        float4 Cq = Cp[q];
#pragma unroll
        for (int j = 0; j < 4; ++j) {
          int s = q * 4 + j;
          float dA = exp2f(dvx * A2[s]);
          h[s] = fmaf(dA, h[s], du * Bq[j]);
          yacc = fmaf(h[s], Cq[j], yacc);
        }
      }
      float sig = 1.f / (1.f + exp2f(zvx * -1.44269504f));
      y[(t0 + t) * DINNER + d] = f2bf((yacc + uvx * Dd) * (zvx * sig));
    }
    __syncthreads();
  }
}

// ---------------- launch ----------------
// Workspace ~190 MiB (round-8-proven size; scan chunk state aliases dead x1n):
//   x1n 25MB [rms1->in_proj]; DEAD during scan -> holds hfin(12.6)+Pp(12.6) exactly;
//            reused again as x2n [rms2->fc1]
//   upre 48MB [in_proj->conv]; reused as delta(bf16) [dtproj->scan]
//   u    48MB [conv->scan];    reused as h1 lower half [fc1->fc2]
//   y    48MB [scan->out_proj];reused as h1 upper half (contiguous with u)
//   xdbl 8MB | A2t 48KB | z -> lives in d_out | weights ~4.3MB
extern "C" void kernel_launch(void* const* d_in, const int* in_sizes, int n_in,
                              void* d_out, int out_size, void* d_ws, size_t ws_size,
                              hipStream_t stream) {
  (void)in_sizes; (void)n_in; (void)out_size; (void)ws_size;
  const float* x       = (const float*)d_in[0];
  const float* norm1_w = (const float*)d_in[1];
  const float* w_in    = (const float*)d_in[2];
  const float* conv_w  = (const float*)d_in[3];
  const float* conv_b  = (const float*)d_in[4];
  const float* w_xproj = (const float*)d_in[5];
  const float* w_dt    = (const float*)d_in[6];
  const float* b_dt    = (const float*)d_in[7];
  const float* A_log   = (const float*)d_in[8];
  const float* Dv      = (const float*)d_in[9];
  const float* w_out   = (const float*)d_in[10];
  const float* norm2_w = (const float*)d_in[11];
  const float* fc1_w   = (const float*)d_in[12];
  const float* fc1_b   = (const float*)d_in[13];
  const float* fc2_w   = (const float*)d_in[14];
  const float* fc2_b   = (const float*)d_in[15];
  float* out = (float*)d_out;

  char* ws = (char*)d_ws;
  size_t off = 0;
  auto alloc = [&](size_t bytes) {
    char* p = ws + off;
    off += (bytes + 255) & ~(size_t)255;
    return p;
  };
  u16* x1n    = (u16*)alloc((size_t)TOKENS * DMODEL * 2);   // also x2n; also hfin+Pp
  u16* upre   = (u16*)alloc((size_t)TOKENS * DINNER * 2);   // also delta (bf16)
  u16* u      = (u16*)alloc((size_t)TOKENS * DINNER * 2);   // also h1[:, :768]
  u16* y      = (u16*)alloc((size_t)TOKENS * DINNER * 2);   // also h1[:, 768:]
  float* xdbl = (float*)alloc((size_t)TOKENS * 64 * 4);
  float* A2t  = (float*)alloc((size_t)DINNER * 16 * 4);
  u16* w_in_h = (u16*)alloc((size_t)1536 * 384 * 2);
  u16* wxp_h  = (u16*)alloc((size_t)64 * 768 * 2);
  u16* wdt_h  = (u16*)alloc((size_t)768 * 24 * 2);
  u16* w_out_h= (u16*)alloc((size_t)384 * 768 * 2);
  u16* fc1_h  = (u16*)alloc((size_t)1536 * 384 * 2);
  u16* fc2_h  = (u16*)alloc((size_t)384 * 1536 * 2);
  u16* z      = (u16*)d_out;     // 32768*768*2 B == 32768*384*4 B exactly
  u16* delta_h = upre;           // upre dead after conv
  u16* h1 = u;                   // u ∥ y, both dead when fc1 writes
  u16* x2n = x1n;                // x1n dead after in_proj
  // scan chunk state aliases x1n (dead between in_proj and rms2):
  // hfin 8*32*16*768*4 = 12.58MB, Pp same; sum == sizeof(x1n) exactly.
  float* hfin = (float*)x1n;
  float* Pp   = hfin + (size_t)NBATCH * NC * 16 * DINNER;

  // weight conversions (each call; ws is re-poisoned every launch)
  k_f2bf<<<256, 256, 0, stream>>>(w_in, w_in_h, 1536 * 384);
  k_pad_wxp<<<(64 * 768 + 255) / 256, 256, 0, stream>>>(w_xproj, wxp_h);
  k_f2bf<<<72, 256, 0, stream>>>(w_dt, wdt_h, 768 * 24);
  k_f2bf<<<256, 256, 0, stream>>>(w_out, w_out_h, 384 * 768);
  k_f2bf<<<256, 256, 0, stream>>>(fc1_w, fc1_h, 1536 * 384);
  k_f2bf<<<256, 256, 0, stream>>>(fc2_w, fc2_h, 384 * 1536);
  k_prepA<<<48, 256, 0, stream>>>(A_log, A2t);

  // 1) rmsnorm1
  k_rmsnorm<<<TOKENS / 4, 256, 0, stream>>>(x, norm1_w, x1n);
  // 2) in_proj -> u_pre, z(in d_out)
  k_gemm_bt<128, 0><<<256 * 12, 256, 0, stream>>>(x1n, w_in_h, 384, 1536, 256,
                                                  nullptr, nullptr, upre, z);
  // 3) conv + silu -> u
  dim3 cgrid(3, 256, 8);
  k_conv<<<cgrid, 256, 0, stream>>>(upre, conv_w, conv_b, u);
  // 4) x_proj -> xdbl (padded stride 64)
  k_gemm_bt<64, 1><<<256 * 1, 256, 0, stream>>>(u, wxp_h, 768, 64, 256,
                                                nullptr, xdbl, nullptr, nullptr);
  // 5) dt_proj + softplus -> delta (bf16, in upre region)
  k_dtproj<<<TOKENS / 32, 256, 0, stream>>>(xdbl, wdt_h, b_dt, delta_h);
  // 6) chunked selective scan -> y   (hfin/Pp live in x1n region, dead here)
  k_scan_a<<<NBATCH * NC * 3, 256, 0, stream>>>(delta_h, u, xdbl, A2t, hfin, Pp);
  k_fixup<<<NBATCH * 16 * DINNER / 256, 256, 0, stream>>>(hfin, Pp);
  k_scan_c<<<NBATCH * NC * 3, 256, 0, stream>>>(delta_h, u, xdbl, z, A2t, Dv, hfin, y);
  // 7) out_proj + residual -> d_out (= x2); overwrites z region
  k_gemm_bt<128, 2><<<256 * 3, 256, 0, stream>>>(y, w_out_h, 768, 384, 256,
                                                 x, out, nullptr, nullptr);
  // 8) rmsnorm2 (x1n region free again)
  k_rmsnorm<<<TOKENS / 4, 256, 0, stream>>>(out, norm2_w, x2n);
  // 9) fc1 + gelu -> h1 (over u∥y)
  k_gemm_bt<128, 3><<<256 * 12, 256, 0, stream>>>(x2n, fc1_h, 384, 1536, 256,
                                                  fc1_b, nullptr, h1, nullptr);
  // 10) fc2 + bias + residual -> d_out
  k_gemm_bt<128, 4><<<256 * 3, 256, 0, stream>>>(h1, fc2_h, 1536, 384, 256,
                                                 fc2_b, out, nullptr, nullptr);
}